// Round 5
// baseline (306.406 us; speedup 1.0000x reference)
//
#include <hip/hip_runtime.h>
#include <hip/hip_bf16.h>

typedef __attribute__((ext_vector_type(8))) short bf16x8;
typedef __attribute__((ext_vector_type(4))) float f32x4;

#define NB 16
#define C 256
#define HH 56
#define WW 56
#define HW 3136
#define CHW 802816
#define NPIX 50176
#define PH 58
#define PW 58
#define KTOT 2304
#define PPI 3364      // 58*58 padded pixels per image
#define NPIXP 53824   // 16*3364 total padded pixels

#define GLL(g, l) __builtin_amdgcn_global_load_lds( \
    (const __attribute__((address_space(1))) void*)(g), \
    (__attribute__((address_space(3))) void*)(l), 16, 0, 0)

// ---------------- kernel 1: BN stats (fp64 accum, float4 loads, 1024 thr) ----------------
__global__ __launch_bounds__(1024) void stats_kernel(const float* __restrict__ x,
                             const float* __restrict__ gamma, double* __restrict__ stats) {
  int c = blockIdx.x, tid = threadIdx.x;
  double s = 0.0, s2 = 0.0;
  const float* xc = x + (size_t)c * HW;
  for (int k = tid; k < NB * (HW / 4); k += 1024) {   // 12544 float4s
    int n = k / (HW / 4), i = k - n * (HW / 4);
    float4 v = *(const float4*)(xc + (size_t)n * CHW + i * 4);
    double a = v.x, b = v.y, cc = v.z, d = v.w;
    s  += (a + b) + (cc + d);
    s2 += (a * a + b * b) + (cc * cc + d * d);
  }
  __shared__ double rs[1024], rq[1024];
  rs[tid] = s; rq[tid] = s2; __syncthreads();
  for (int o = 512; o > 0; o >>= 1) {
    if (tid < o) { rs[tid] += rs[tid + o]; rq[tid] += rq[tid + o]; }
    __syncthreads();
  }
  if (tid == 0) {
    double mean = rs[0] / (double)NPIX;
    double var = rq[0] / (double)NPIX - mean * mean;
    stats[c] = mean;
    stats[C + c] = (double)gamma[c] / sqrt(var + 1e-4);
  }
}

// ------- kernel 2: ternarize -> padded NHWC (channel-permuted) bf16 Tp + c_sum -------
// channel permutation: slot p = (c&31)*8 + (c>>5)  <->  c = (p&7)*32 + (p>>3)
__global__ __launch_bounds__(256) void ternarize_kernel(const float* __restrict__ x,
                                 const float* __restrict__ beta,
                                 const double* __restrict__ stats,
                                 unsigned short* __restrict__ Tp, float* __restrict__ csum) {
  int bid = blockIdx.x, tid = threadIdx.x;
  int n = bid / HH, h = bid - n * HH;
  __shared__ float xs[256][57];   // stride 57: transposed reads conflict-free
  const float* xb = x + (size_t)n * CHW + h * WW;
#pragma unroll
  for (int j = 0; j < 14; ++j) {
    int idx = j * 256 + tid;
    int c = idx / 14, q = idx - c * 14;
    float4 v = *(const float4*)(xb + (size_t)c * HW + q * 4);
    float* row = &xs[c][q * 4];
    row[0] = v.x; row[1] = v.y; row[2] = v.z; row[3] = v.w;
  }
  int c8 = tid & 31;
  double mu[8], sc[8], bt[8];
#pragma unroll
  for (int e = 0; e < 8; ++e) {
    int c = c8 + 32 * e;
    mu[e] = stats[c]; sc[e] = stats[C + c]; bt[e] = (double)beta[c];
  }
  __syncthreads();
  unsigned short* tb = Tp + ((size_t)(n * PH + h + 1) * PW + 1) * C;
  float* cs = csum + (size_t)(n * PH + h + 1) * PW + 1;
#pragma unroll
  for (int p = 0; p < 7; ++p) {
    int idx = p * 256 + tid;
    int w = idx >> 5;
    unsigned bits[4];
    float msum = 0.f;
#pragma unroll
    for (int e2 = 0; e2 < 4; ++e2) {
      unsigned lo, hi;
      {
        double xn = ((double)xs[c8 + 64 * e2][w] - mu[2 * e2]) * sc[2 * e2] + bt[2 * e2];
        lo = (xn > 0.0) ? 0x3F80u : 0xBF80u;
        msum += (float)fmin(fabs(xn), 1.0);
      }
      {
        double xn = ((double)xs[c8 + 64 * e2 + 32][w] - mu[2 * e2 + 1]) * sc[2 * e2 + 1] + bt[2 * e2 + 1];
        hi = (xn > 0.0) ? 0x3F80u : 0xBF80u;
        msum += (float)fmin(fabs(xn), 1.0);
      }
      bits[e2] = lo | (hi << 16);
    }
    msum += __shfl_xor(msum, 1); msum += __shfl_xor(msum, 2);
    msum += __shfl_xor(msum, 4); msum += __shfl_xor(msum, 8);
    msum += __shfl_xor(msum, 16);
    uint4 v4; v4.x = bits[0]; v4.y = bits[1]; v4.z = bits[2]; v4.w = bits[3];
    *(uint4*)(tb + (size_t)w * C + c8 * 8) = v4;
    if (c8 == 0) cs[w] = msum;
  }
}

// ------- kernel 2b (fused prep): wprep + Tp border zero + csum zero -------
__global__ void prep_kernel(const float* __restrict__ cw, unsigned short* __restrict__ Wp,
                            unsigned short* __restrict__ Tp, float* __restrict__ csum) {
  int b = blockIdx.x, tid = threadIdx.x;
  if (b < 2304) {
    // weights OIHW -> [co][tap][perm(c)] bf16 (RNE)
    int o = b * 256 + tid;  // < 589824
    int co = o / KTOT, rr = o - co * KTOT;
    int tap = rr >> 8, p = rr & 255;
    int c = (p & 7) * 32 + (p >> 3);         // inverse permutation
    float v = cw[co * KTOT + c * 9 + tap];
    unsigned u = __builtin_bit_cast(unsigned, v);
    unsigned lsb = (u >> 16) & 1u;
    u += 0x7FFFu + lsb;
    Wp[o] = (unsigned short)(u >> 16);
  } else if (b < 2760) {
    int g = (b - 2304) * 256 + tid;  // 456*256 >= 116736 = 16*228*32
    if (g >= 16 * 228 * 32) return;
    int n = g / 7296; int r = g - n * 7296;
    int pix = r >> 5, c8 = r & 31;
    int h, w;
    if (pix < 58)      { h = 0;  w = pix; }
    else if (pix < 116){ h = 57; w = pix - 58; }
    else { int rem = pix - 116; h = 1 + (rem >> 1); w = (rem & 1) ? 57 : 0; }
    uint4 z = {0u, 0u, 0u, 0u};
    *(uint4*)(Tp + (size_t)((n * PH + h) * PW + w) * C + c8 * 8) = z;
  } else {
    int i = (b - 2760) * 256 + tid;
    if (i < NPIXP) csum[i] = 0.f;
  }
}

// ------- kernel 4: beta_map per pixel -------
__global__ void betamap_kernel(const float* __restrict__ csum, const float* __restrict__ betab,
                               float* __restrict__ bmap) {
  int idx = blockIdx.x * 256 + threadIdx.x;
  if (idx >= NPIX) return;
  int n = idx / HW, r = idx - n * HW;
  int h = r / WW, w = r - h * WW;
  const float* p = csum + (size_t)(n * PH + h) * PW + w;
  float s = 0.f;
  for (int i = 0; i < 3; ++i)
    for (int j = 0; j < 3; ++j) s += p[i * PW + j];
  int rows = 3 - (h == 0) - (h == HH - 1);
  int cols = 3 - (w == 0) - (w == WW - 1);
  float bb = betab[0];
  bmap[idx] = (s + bb) / (256.0f * (float)(rows * cols) + bb);
}

// ------- kernel 5: windowed implicit-GEMM ternary conv, 9 taps from LDS -------
// Tile: M=64 co x N=256 padded pixels. Per c-chunk(32): stage A = As[tap][co][seg]
// (9 uniform GLL rounds, NO divergence, XOR-seg swizzle) + B (384-pixel window x 32c,
// VGPR->LDS, stride-36 pad), then 9 taps x 16 MFMA per wave between one barrier pair.
__global__ __launch_bounds__(256) void conv_kernel(const unsigned short* __restrict__ Wp,
    const unsigned short* __restrict__ Tp, const float* __restrict__ convb,
    const float* __restrict__ bmap, float* __restrict__ out) {
  int bid = blockIdx.x;
  int ptg = bid >> 5, xcd = bid & 7, ct = (bid >> 3) & 3;
  int pt = ptg * 8 + xcd;                    // pixel tile (same-XCD blocks share it)
  if (pt >= 211) return;
  int tid = threadIdx.x;
  int co0 = ct * 64;
  int pwin0 = pt * 256 - 64;                 // window start in padded pixel space

  __shared__ __align__(16) unsigned short As[9 * 256 * 8];   // 36864 B: [tap][co][seg]
  __shared__ __align__(16) unsigned short Bs[384 * 36];      // 27648 B, stride 36 pad

  // ---- A staging plan: lane tid -> co = tid>>2, physical seg = tid&3,
  //      logical seg (channel group) = (tid&3) ^ (co&3)   [XOR swizzle]
  int aco = tid >> 2;
  int asg = (tid & 3) ^ (aco & 3);
  size_t aofs0 = (size_t)(co0 + aco) * KTOT + asg * 8;   // + tap*256 + c0
  unsigned short* adst0 = As + tid * 8;                  // + tap*2048

  // ---- B staging plan (VGPR round-trip, padded LDS stride) ----
  int bofs[6]; unsigned short* bdst[6];
#pragma unroll
  for (int i = 0; i < 6; ++i) {
    int lin = i * 256 + tid;
    int pix = lin >> 2, sg = lin & 3;
    int p = pwin0 + pix;
    p = p < 0 ? 0 : (p >= NPIXP ? NPIXP - 1 : p);
    bofs[i] = p * C + sg * 8;
    bdst[i] = Bs + pix * 36 + sg * 8;
  }

  int lane = tid & 63, wid = tid >> 6;
  int quad = lane >> 4, row16 = lane & 15;
  // A fragment base: element = tap*2048 + (mi*16+row16)*32 + (quad^(row16&3))*8
  const unsigned short* aF = As + row16 * 32 + (quad ^ (row16 & 3)) * 8;   // +tap*2048 +mi*512
  const unsigned short* bF = Bs + (wid * 64 + 64 + row16) * 36 + quad * 8; // +(ni*16+dt)*36

  f32x4 acc[4][4];
#pragma unroll
  for (int mi = 0; mi < 4; ++mi)
#pragma unroll
    for (int ni = 0; ni < 4; ++ni)
      acc[mi][ni] = (f32x4){0.f, 0.f, 0.f, 0.f};

  for (int c0 = 0; c0 < 256; c0 += 32) {
    __syncthreads();
    uint4 breg[6];
#pragma unroll
    for (int i = 0; i < 6; ++i) breg[i] = *(const uint4*)(Tp + (size_t)bofs[i] + c0);
#pragma unroll
    for (int tap = 0; tap < 9; ++tap)
      GLL(Wp + aofs0 + tap * 256 + c0, adst0 + tap * 2048);
#pragma unroll
    for (int i = 0; i < 6; ++i) *(uint4*)bdst[i] = breg[i];
    __syncthreads();
#pragma unroll
    for (int tap = 0; tap < 9; ++tap) {
      const int dt = (tap / 3 - 1) * PW + (tap % 3 - 1);
      bf16x8 a[4], b[4];
#pragma unroll
      for (int mi = 0; mi < 4; ++mi) a[mi] = *(const bf16x8*)(aF + tap * 2048 + mi * 512);
#pragma unroll
      for (int ni = 0; ni < 4; ++ni) b[ni] = *(const bf16x8*)(bF + (ni * 16 + dt) * 36);
#pragma unroll
      for (int mi = 0; mi < 4; ++mi)
#pragma unroll
        for (int ni = 0; ni < 4; ++ni)
          acc[mi][ni] = __builtin_amdgcn_mfma_f32_16x16x32_bf16(a[mi], b[ni], acc[mi][ni], 0, 0, 0);
    }
  }

  // epilogue: out = (acc + conv_b) * beta_map ; skip padded-border/garbage outputs
#pragma unroll
  for (int ni = 0; ni < 4; ++ni) {
    int pp = pt * 256 + wid * 64 + ni * 16 + row16;
    if (pp >= NPIXP) continue;
    int n = pp / PPI; int r = pp - n * PPI;
    int ph = r / PW;  int pw = r - ph * PW;
    if (ph < 1 || ph > 56 || pw < 1 || pw > 56) continue;
    int pix = (ph - 1) * WW + (pw - 1);
    float bm = bmap[n * HW + pix];
    float* ob = out + (size_t)n * CHW + pix;
#pragma unroll
    for (int mi = 0; mi < 4; ++mi) {
      int co = co0 + mi * 16 + quad * 4;
#pragma unroll
      for (int rg = 0; rg < 4; ++rg) {
        ob[(size_t)(co + rg) * HW] = (acc[mi][ni][rg] + convb[co + rg]) * bm;
      }
    }
  }
}

extern "C" void kernel_launch(void* const* d_in, const int* in_sizes, int n_in,
                              void* d_out, int out_size, void* d_ws, size_t ws_size,
                              hipStream_t stream) {
  const float* x     = (const float*)d_in[0];
  const float* gamma = (const float*)d_in[1];
  const float* beta  = (const float*)d_in[2];
  const float* convw = (const float*)d_in[3];
  const float* convb = (const float*)d_in[4];
  const float* betab = (const float*)d_in[5];
  float* out = (float*)d_out;

  char* ws = (char*)d_ws;
  unsigned short* Tp   = (unsigned short*)(ws);                 // 16*58*58*256*2 = 27,557,888
  unsigned short* Wp   = (unsigned short*)(ws + 27557888);      // 256*2304*2     =  1,179,648
  float*          csum = (float*)(ws + 28737536);               // 16*58*58*4     =    215,296
  float*          bmap = (float*)(ws + 28952832);               // 50176*4        =    200,704
  double*         stats= (double*)(ws + 29153536);              // 512*8          =      4,096

  prep_kernel<<<2971, 256, 0, stream>>>(convw, Wp, Tp, csum);
  stats_kernel<<<256, 1024, 0, stream>>>(x, gamma, stats);
  ternarize_kernel<<<896, 256, 0, stream>>>(x, beta, stats, Tp, csum);
  betamap_kernel<<<196, 256, 0, stream>>>(csum, betab, bmap);
  conv_kernel<<<864, 256, 0, stream>>>(Wp, Tp, convb, bmap, out);
}

// Round 6
// 204.674 us; speedup vs baseline: 1.4970x; 1.4970x over previous
//
#include <hip/hip_runtime.h>
#include <hip/hip_bf16.h>

typedef __attribute__((ext_vector_type(8))) short bf16x8;
typedef __attribute__((ext_vector_type(4))) float f32x4;

#define NB 16
#define C 256
#define HH 56
#define WW 56
#define HW 3136
#define CHW 802816
#define NPIX 50176
#define PH 58
#define PW 58
#define KTOT 2304
#define PPI 3364      // 58*58 padded pixels per image
#define NPIXP 53824   // 16*3364 total padded pixels

#define GLL(g, l) __builtin_amdgcn_global_load_lds( \
    (const __attribute__((address_space(1))) void*)(g), \
    (__attribute__((address_space(3))) void*)(l), 16, 0, 0)

// ---------------- kernel 1: BN stats (fp64 accum, float4 loads, 1024 thr) ----------------
__global__ __launch_bounds__(1024) void stats_kernel(const float* __restrict__ x,
                             const float* __restrict__ gamma, double* __restrict__ stats) {
  int c = blockIdx.x, tid = threadIdx.x;
  double s = 0.0, s2 = 0.0;
  const float* xc = x + (size_t)c * HW;
  for (int k = tid; k < NB * (HW / 4); k += 1024) {   // 12544 float4s
    int n = k / (HW / 4), i = k - n * (HW / 4);
    float4 v = *(const float4*)(xc + (size_t)n * CHW + i * 4);
    double a = v.x, b = v.y, cc = v.z, d = v.w;
    s  += (a + b) + (cc + d);
    s2 += (a * a + b * b) + (cc * cc + d * d);
  }
  __shared__ double rs[1024], rq[1024];
  rs[tid] = s; rq[tid] = s2; __syncthreads();
  for (int o = 512; o > 0; o >>= 1) {
    if (tid < o) { rs[tid] += rs[tid + o]; rq[tid] += rq[tid + o]; }
    __syncthreads();
  }
  if (tid == 0) {
    double mean = rs[0] / (double)NPIX;
    double var = rq[0] / (double)NPIX - mean * mean;
    stats[c] = mean;
    stats[C + c] = (double)gamma[c] / sqrt(var + 1e-4);
  }
}

// ------- kernel 2: ternarize -> padded NHWC (channel-permuted) bf16 Tp + c_sum -------
// channel permutation: slot p = (c&31)*8 + (c>>5)  <->  c = (p&7)*32 + (p>>3)
__global__ __launch_bounds__(256) void ternarize_kernel(const float* __restrict__ x,
                                 const float* __restrict__ beta,
                                 const double* __restrict__ stats,
                                 unsigned short* __restrict__ Tp, float* __restrict__ csum) {
  int bid = blockIdx.x, tid = threadIdx.x;
  int n = bid / HH, h = bid - n * HH;
  __shared__ float xs[256][57];   // stride 57: transposed reads conflict-free
  const float* xb = x + (size_t)n * CHW + h * WW;
#pragma unroll
  for (int j = 0; j < 14; ++j) {
    int idx = j * 256 + tid;
    int c = idx / 14, q = idx - c * 14;
    float4 v = *(const float4*)(xb + (size_t)c * HW + q * 4);
    float* row = &xs[c][q * 4];
    row[0] = v.x; row[1] = v.y; row[2] = v.z; row[3] = v.w;
  }
  int c8 = tid & 31;
  double mu[8], sc[8], bt[8];
#pragma unroll
  for (int e = 0; e < 8; ++e) {
    int c = c8 + 32 * e;
    mu[e] = stats[c]; sc[e] = stats[C + c]; bt[e] = (double)beta[c];
  }
  __syncthreads();
  unsigned short* tb = Tp + ((size_t)(n * PH + h + 1) * PW + 1) * C;
  float* cs = csum + (size_t)(n * PH + h + 1) * PW + 1;
#pragma unroll
  for (int p = 0; p < 7; ++p) {
    int idx = p * 256 + tid;
    int w = idx >> 5;
    unsigned bits[4];
    float msum = 0.f;
#pragma unroll
    for (int e2 = 0; e2 < 4; ++e2) {
      unsigned lo, hi;
      {
        double xn = ((double)xs[c8 + 64 * e2][w] - mu[2 * e2]) * sc[2 * e2] + bt[2 * e2];
        lo = (xn > 0.0) ? 0x3F80u : 0xBF80u;
        msum += (float)fmin(fabs(xn), 1.0);
      }
      {
        double xn = ((double)xs[c8 + 64 * e2 + 32][w] - mu[2 * e2 + 1]) * sc[2 * e2 + 1] + bt[2 * e2 + 1];
        hi = (xn > 0.0) ? 0x3F80u : 0xBF80u;
        msum += (float)fmin(fabs(xn), 1.0);
      }
      bits[e2] = lo | (hi << 16);
    }
    msum += __shfl_xor(msum, 1); msum += __shfl_xor(msum, 2);
    msum += __shfl_xor(msum, 4); msum += __shfl_xor(msum, 8);
    msum += __shfl_xor(msum, 16);
    uint4 v4; v4.x = bits[0]; v4.y = bits[1]; v4.z = bits[2]; v4.w = bits[3];
    *(uint4*)(tb + (size_t)w * C + c8 * 8) = v4;
    if (c8 == 0) cs[w] = msum;
  }
}

// ------- kernel 2b (fused prep): wprep + Tp border zero + csum zero -------
__global__ void prep_kernel(const float* __restrict__ cw, unsigned short* __restrict__ Wp,
                            unsigned short* __restrict__ Tp, float* __restrict__ csum) {
  int b = blockIdx.x, tid = threadIdx.x;
  if (b < 2304) {
    // weights OIHW -> [co][tap][perm(c)] bf16 (RNE)
    int o = b * 256 + tid;  // < 589824
    int co = o / KTOT, rr = o - co * KTOT;
    int tap = rr >> 8, p = rr & 255;
    int c = (p & 7) * 32 + (p >> 3);         // inverse permutation
    float v = cw[co * KTOT + c * 9 + tap];
    unsigned u = __builtin_bit_cast(unsigned, v);
    unsigned lsb = (u >> 16) & 1u;
    u += 0x7FFFu + lsb;
    Wp[o] = (unsigned short)(u >> 16);
  } else if (b < 2760) {
    int g = (b - 2304) * 256 + tid;  // 456*256 >= 116736 = 16*228*32
    if (g >= 16 * 228 * 32) return;
    int n = g / 7296; int r = g - n * 7296;
    int pix = r >> 5, c8 = r & 31;
    int h, w;
    if (pix < 58)      { h = 0;  w = pix; }
    else if (pix < 116){ h = 57; w = pix - 58; }
    else { int rem = pix - 116; h = 1 + (rem >> 1); w = (rem & 1) ? 57 : 0; }
    uint4 z = {0u, 0u, 0u, 0u};
    *(uint4*)(Tp + (size_t)((n * PH + h) * PW + w) * C + c8 * 8) = z;
  } else {
    int i = (b - 2760) * 256 + tid;
    if (i < NPIXP) csum[i] = 0.f;
  }
}

// ------- kernel 4: beta_map per pixel -------
__global__ void betamap_kernel(const float* __restrict__ csum, const float* __restrict__ betab,
                               float* __restrict__ bmap) {
  int idx = blockIdx.x * 256 + threadIdx.x;
  if (idx >= NPIX) return;
  int n = idx / HW, r = idx - n * HW;
  int h = r / WW, w = r - h * WW;
  const float* p = csum + (size_t)(n * PH + h) * PW + w;
  float s = 0.f;
  for (int i = 0; i < 3; ++i)
    for (int j = 0; j < 3; ++j) s += p[i * PW + j];
  int rows = 3 - (h == 0) - (h == HH - 1);
  int cols = 3 - (w == 0) - (w == WW - 1);
  float bb = betab[0];
  bmap[idx] = (s + bb) / (256.0f * (float)(rows * cols) + bb);
}

// ------- kernel 5: kh-split windowed implicit-GEMM ternary conv -------
// Tile: M=64 co x N=256 padded pixels. Outer loop kh(3) x c-chunk(8) = 24 stages.
// Per stage: A = As[3tap][64co][32c] (12.3 KB) + B = Bs[320pix][32c] (20.5 KB), both
// staged with pure GLL (no VGPR round trip); XOR-on-global-segment permutation
// seg^((idx>>1)&3) makes every 8-lane b128 phase cover all 32 banks (conflict-free).
// LDS = 32768 B exactly -> 4 blocks/CU. 3 taps x 16 MFMA per wave between barriers.
__global__ __launch_bounds__(256) void conv_kernel(const unsigned short* __restrict__ Wp,
    const unsigned short* __restrict__ Tp, const float* __restrict__ convb,
    const float* __restrict__ bmap, float* __restrict__ out) {
  int bid = blockIdx.x;
  int ptg = bid >> 5, xcd = bid & 7, ct = (bid >> 3) & 3;
  int pt = ptg * 8 + xcd;                    // pixel tile (same-XCD blocks share it)
  if (pt >= 211) return;
  int tid = threadIdx.x;
  int co0 = ct * 64;

  __shared__ __align__(16) unsigned short As[3 * 64 * 32];   // 12288 B
  __shared__ __align__(16) unsigned short Bs[320 * 32];      // 20480 B

  // ---- A staging plan: 3 GLL rounds, lin = r*256+tid -> [tap3][co][physseg]
  size_t aofs[3];
#pragma unroll
  for (int r = 0; r < 3; ++r) {
    int lin = r * 256 + tid;
    int co = (lin >> 2) & 63, tap3 = lin >> 8, pseg = lin & 3;
    int lseg = pseg ^ ((co >> 1) & 3);
    aofs[r] = (size_t)(co0 + co) * KTOT + tap3 * 256 + lseg * 8;  // + kh*768 + c0
  }
  // ---- B staging plan: 5 GLL rounds, lin = r*256+tid -> [pix][physseg]
  int bpix[5], blseg[5];
#pragma unroll
  for (int r = 0; r < 5; ++r) {
    int lin = r * 256 + tid;
    bpix[r] = lin >> 2;
    blseg[r] = (lin & 3) ^ ((bpix[r] >> 1) & 3);
  }

  int lane = tid & 63, wid = tid >> 6;
  int quad = lane >> 4, row16 = lane & 15;
  int aperm = (quad ^ ((row16 >> 1) & 3)) * 8;
  const unsigned short* aF = As + row16 * 32 + aperm;   // + kw*2048 + mi*512
  int jbase = wid * 64 + row16 + 31;                    // + ni*16 + kw -> staged B row

  f32x4 acc[4][4];
#pragma unroll
  for (int mi = 0; mi < 4; ++mi)
#pragma unroll
    for (int ni = 0; ni < 4; ++ni)
      acc[mi][ni] = (f32x4){0.f, 0.f, 0.f, 0.f};

  for (int kh = 0; kh < 3; ++kh) {
    int wbase = pt * 256 + (kh - 1) * 58 - 32;          // window start (padded pixels)
    // per-kh B global element offsets (clamped)
    size_t bofs[5];
#pragma unroll
    for (int r = 0; r < 5; ++r) {
      int q = wbase + bpix[r];
      q = q < 0 ? 0 : (q >= NPIXP ? NPIXP - 1 : q);
      bofs[r] = (size_t)q * C + blseg[r] * 8;
    }
    size_t akh = (size_t)kh * 768;
    for (int c0 = 0; c0 < 256; c0 += 32) {
      __syncthreads();
#pragma unroll
      for (int r = 0; r < 3; ++r) GLL(Wp + aofs[r] + akh + c0, As + (r * 256 + tid) * 8);
#pragma unroll
      for (int r = 0; r < 5; ++r) GLL(Tp + bofs[r] + c0, Bs + (r * 256 + tid) * 8);
      __syncthreads();
#pragma unroll
      for (int kw = 0; kw < 3; ++kw) {
        bf16x8 a[4], b[4];
#pragma unroll
        for (int mi = 0; mi < 4; ++mi)
          a[mi] = *(const bf16x8*)(aF + kw * 2048 + mi * 512);
#pragma unroll
        for (int ni = 0; ni < 4; ++ni) {
          int pix = jbase + ni * 16 + kw;
          b[ni] = *(const bf16x8*)(Bs + pix * 32 + ((quad ^ ((pix >> 1) & 3)) * 8));
        }
#pragma unroll
        for (int mi = 0; mi < 4; ++mi)
#pragma unroll
          for (int ni = 0; ni < 4; ++ni)
            acc[mi][ni] = __builtin_amdgcn_mfma_f32_16x16x32_bf16(a[mi], b[ni], acc[mi][ni], 0, 0, 0);
      }
    }
  }

  // epilogue: out = (acc + conv_b) * beta_map ; skip padded-border/garbage outputs
#pragma unroll
  for (int ni = 0; ni < 4; ++ni) {
    int pp = pt * 256 + wid * 64 + ni * 16 + row16;
    if (pp >= NPIXP) continue;
    int n = pp / PPI; int r = pp - n * PPI;
    int ph = r / PW;  int pw = r - ph * PW;
    if (ph < 1 || ph > 56 || pw < 1 || pw > 56) continue;
    int pix = (ph - 1) * WW + (pw - 1);
    float bm = bmap[n * HW + pix];
    float* ob = out + (size_t)n * CHW + pix;
#pragma unroll
    for (int mi = 0; mi < 4; ++mi) {
      int co = co0 + mi * 16 + quad * 4;
#pragma unroll
      for (int rg = 0; rg < 4; ++rg) {
        ob[(size_t)(co + rg) * HW] = (acc[mi][ni][rg] + convb[co + rg]) * bm;
      }
    }
  }
}

extern "C" void kernel_launch(void* const* d_in, const int* in_sizes, int n_in,
                              void* d_out, int out_size, void* d_ws, size_t ws_size,
                              hipStream_t stream) {
  const float* x     = (const float*)d_in[0];
  const float* gamma = (const float*)d_in[1];
  const float* beta  = (const float*)d_in[2];
  const float* convw = (const float*)d_in[3];
  const float* convb = (const float*)d_in[4];
  const float* betab = (const float*)d_in[5];
  float* out = (float*)d_out;

  char* ws = (char*)d_ws;
  unsigned short* Tp   = (unsigned short*)(ws);                 // 16*58*58*256*2 = 27,557,888
  unsigned short* Wp   = (unsigned short*)(ws + 27557888);      // 256*2304*2     =  1,179,648
  float*          csum = (float*)(ws + 28737536);               // 16*58*58*4     =    215,296
  float*          bmap = (float*)(ws + 28952832);               // 50176*4        =    200,704
  double*         stats= (double*)(ws + 29153536);              // 512*8          =      4,096

  prep_kernel<<<2971, 256, 0, stream>>>(convw, Wp, Tp, csum);
  stats_kernel<<<256, 1024, 0, stream>>>(x, gamma, stats);
  ternarize_kernel<<<896, 256, 0, stream>>>(x, beta, stats, Tp, csum);
  betamap_kernel<<<196, 256, 0, stream>>>(csum, betab, bmap);
  conv_kernel<<<864, 256, 0, stream>>>(Wp, Tp, convb, bmap, out);
}